// Round 4
// baseline (1027.652 us; speedup 1.0000x reference)
//
#include <hip/hip_runtime.h>
#include <stdint.h>

typedef __attribute__((ext_vector_type(8))) __bf16 bf16x8;
typedef __attribute__((ext_vector_type(4))) float floatx4;

#define GLOBAL_AS __attribute__((address_space(1)))
#define LDS_AS __attribute__((address_space(3)))

#define CAP 96          // edge bucket capacity per row (Poisson lambda=16 -> overflow P ~1e-14)
#define N1 15001        // graph rows
#define NPAD 15104      // 118 * 128

__device__ __forceinline__ unsigned short f2bf(float x) {
  unsigned int u = __builtin_bit_cast(unsigned int, x);
  u += 0x7FFFu + ((u >> 16) & 1u);   // round-to-nearest-even
  return (unsigned short)(u >> 16);
}
__device__ __forceinline__ unsigned int pk2(float lo, float hi) {
  return (unsigned)f2bf(lo) | ((unsigned)f2bf(hi) << 16);
}

// Stage a 128x32 bf16 tile (row-major, ld) into LDS chunks[kg][m], kg=k>>3,
// each chunk 16B. global_load_lds w=16: dst = wave-uniform base + lane*16.
// Issues exactly 2 vmem instructions per wave.
__device__ __forceinline__ void stage_tile(const unsigned short* g, int ld, int row0, int k0,
                                           bf16x8* lds, int tid) {
  const int lane = tid & 63;
  const int w = tid >> 6;
#pragma unroll
  for (int j = 0; j < 2; ++j) {
    const int c = j * 256 + w * 64;        // wave-uniform chunk base
    const int kg = c >> 7;
    const int mbase = c & 127;
    const unsigned short* src = g + ((size_t)(row0 + mbase + lane) * ld + k0 + kg * 8);
    __builtin_amdgcn_global_load_lds((const GLOBAL_AS void*)src, (LDS_AS void*)(lds + c),
                                     16, 0, 0);
  }
}

// C = A(MxK) * B(NxK)^T, K=1024, 128x128 tile, 256 thr (4 waves 2x2), 4x4 16x16x32 MFMA.
// MODE 1/2/3: 3-buffer LDS, 2-deep prefetch, counted vmcnt (T3+T4) — loads stay in
// flight across barriers; never drain vmcnt to 0 in the main loop.
// Bijective y-stripe XCD swizzle (needs gridDim.y % 8 == 0): all gridDim.x
// col-blocks of one row-panel run consecutively on the same XCD -> A-panel L2 reuse.
// MODE 0: A is FP32 (manual convert-stage, __syncthreads dbuf); epilogue pooled-max
// MODE 1: A bf16; epilogue bias+relu -> fp32 outF (ld 1024)
// MODE 2: A bf16; plain fp32 store, ld nValid, col guard
// MODE 3: A bf16; epilogue bias+max-over-32rows+relu -> bf16 pooled
template <int MODE>
__launch_bounds__(256, 2)
__global__ void gemm_bt(const void* __restrict__ Aptr,
                        const unsigned short* __restrict__ Bm,
                        const float* __restrict__ bias,
                        float* __restrict__ outF,
                        unsigned short* __restrict__ outU,
                        int nValid) {
  __shared__ bf16x8 As[3][512];   // [buf][kg][m] chunks, 24 KB
  __shared__ bf16x8 Bs[3][512];   // 48 KB total -> still 2 blocks/CU
  const int tid = threadIdx.x;
  const int lane = tid & 63;
  const int w = tid >> 6;
  const int wm = w >> 1, wn = w & 1;
  const int quad = lane >> 4, col = lane & 15;

  int bx = blockIdx.x, by = blockIdx.y;
  if ((gridDim.y & 7) == 0) {
    const unsigned L = (unsigned)by * gridDim.x + bx;   // original linear id
    const unsigned i = L >> 3, xk = L & 7;              // xcd = L % 8 (round-robin)
    bx = i % gridDim.x;
    by = (i / gridDim.x) * 8 + xk;                      // bijective: gy % 8 == 0
  }
  const int m0 = by * 128, n0 = bx * 128;
  const int K = 1024;

  floatx4 acc[4][4];
#pragma unroll
  for (int a = 0; a < 4; ++a)
#pragma unroll
    for (int b = 0; b < 4; ++b) acc[a][b] = 0;

  if (MODE == 0) {
    // fallback: fp32 A convert-stage, __syncthreads double buffer
    auto stage0 = [&](int buf, int k0) {
      const int row = tid >> 1, kh = tid & 1;
      const float* src = (const float*)Aptr + (size_t)(m0 + row) * K + k0 + kh * 16;
      float4 v0 = ((const float4*)src)[0];
      float4 v1 = ((const float4*)src)[1];
      float4 v2 = ((const float4*)src)[2];
      float4 v3 = ((const float4*)src)[3];
      stage_tile(Bm, K, n0, k0, Bs[buf], tid);
      uint4 c0, c1;
      c0.x = pk2(v0.x, v0.y); c0.y = pk2(v0.z, v0.w);
      c0.z = pk2(v1.x, v1.y); c0.w = pk2(v1.z, v1.w);
      c1.x = pk2(v2.x, v2.y); c1.y = pk2(v2.z, v2.w);
      c1.z = pk2(v3.x, v3.y); c1.w = pk2(v3.z, v3.w);
      ((uint4*)As[buf])[(kh * 2) * 128 + row] = c0;
      ((uint4*)As[buf])[(kh * 2 + 1) * 128 + row] = c1;
    };
    stage0(0, 0);
    int cur = 0;
    for (int k0 = 0; k0 < K; k0 += 32) {
      __syncthreads();
      if (k0 + 32 < K) stage0(cur ^ 1, k0 + 32);
      bf16x8 af[4], bfr[4];
#pragma unroll
      for (int t = 0; t < 4; ++t) af[t] = As[cur][quad * 128 + wm * 64 + t * 16 + col];
#pragma unroll
      for (int t = 0; t < 4; ++t) bfr[t] = Bs[cur][quad * 128 + wn * 64 + t * 16 + col];
#pragma unroll
      for (int mt = 0; mt < 4; ++mt)
#pragma unroll
        for (int nt = 0; nt < 4; ++nt)
          acc[mt][nt] = __builtin_amdgcn_mfma_f32_16x16x32_bf16(af[mt], bfr[nt], acc[mt][nt], 0, 0, 0);
      cur ^= 1;
    }
  } else {
    // pipelined: 2-deep prefetch, 4 global_load_lds per wave per tile
    const unsigned short* Am = (const unsigned short*)Aptr;
    stage_tile(Am, K, m0, 0, As[0], tid);
    stage_tile(Bm, K, n0, 0, Bs[0], tid);
    stage_tile(Am, K, m0, 32, As[1], tid);
    stage_tile(Bm, K, n0, 32, Bs[1], tid);
    int cur = 0;
    for (int k0 = 0; k0 < K; k0 += 32) {
      if (k0 + 32 < K) {
        asm volatile("s_waitcnt vmcnt(4)" ::: "memory");   // tile t landed, t+1 in flight
      } else {
        asm volatile("s_waitcnt vmcnt(0)" ::: "memory");   // last tile: drain
      }
      __builtin_amdgcn_s_barrier();
      __builtin_amdgcn_sched_barrier(0);
      if (k0 + 64 < K) {
        int nb = cur + 2; if (nb >= 3) nb -= 3;
        stage_tile(Am, K, m0, k0 + 64, As[nb], tid);
        stage_tile(Bm, K, n0, k0 + 64, Bs[nb], tid);
      }
      bf16x8 af[4], bfr[4];
#pragma unroll
      for (int t = 0; t < 4; ++t) af[t] = As[cur][quad * 128 + wm * 64 + t * 16 + col];
#pragma unroll
      for (int t = 0; t < 4; ++t) bfr[t] = Bs[cur][quad * 128 + wn * 64 + t * 16 + col];
#pragma unroll
      for (int mt = 0; mt < 4; ++mt)
#pragma unroll
        for (int nt = 0; nt < 4; ++nt)
          acc[mt][nt] = __builtin_amdgcn_mfma_f32_16x16x32_bf16(af[mt], bfr[nt], acc[mt][nt], 0, 0, 0);
      if (++cur == 3) cur = 0;
    }
  }

  // D layout: row = quad*4 + reg, col = lane&15
  if (MODE == 0 || MODE == 3) {
    float bv[4];
#pragma unroll
    for (int nt = 0; nt < 4; ++nt) bv[nt] = bias[n0 + wn * 64 + nt * 16 + col];
#pragma unroll
    for (int g = 0; g < 2; ++g) {          // two 32-row (one-seq) groups per wave
#pragma unroll
      for (int nt = 0; nt < 4; ++nt) {
        float v = -3.4e38f;
#pragma unroll
        for (int mh = 0; mh < 2; ++mh) {
          const int mt = 2 * g + mh;
#pragma unroll
          for (int r = 0; r < 4; ++r) v = fmaxf(v, acc[mt][nt][r]);
        }
        v += bv[nt];                        // max(x)+b == max(x+b)
        v = fmaxf(v, __shfl_xor(v, 16, 64));
        v = fmaxf(v, __shfl_xor(v, 32, 64));
        v = fmaxf(v, 0.0f);                 // relu after max (monotone)
        if (quad == 0) {
          const int b = (m0 >> 5) + wm * 2 + g;
          outU[b * 1024 + n0 + wn * 64 + nt * 16 + col] = f2bf(v);
        }
      }
    }
  } else if (MODE == 1) {
    float bv[4];
#pragma unroll
    for (int nt = 0; nt < 4; ++nt) bv[nt] = bias[n0 + wn * 64 + nt * 16 + col];
#pragma unroll
    for (int mt = 0; mt < 4; ++mt)
#pragma unroll
      for (int r = 0; r < 4; ++r) {
        const int row = m0 + wm * 64 + mt * 16 + quad * 4 + r;
#pragma unroll
        for (int nt = 0; nt < 4; ++nt)
          outF[(size_t)row * 1024 + n0 + wn * 64 + nt * 16 + col] =
              fmaxf(acc[mt][nt][r] + bv[nt], 0.0f);
      }
  } else {
#pragma unroll
    for (int mt = 0; mt < 4; ++mt)
#pragma unroll
      for (int r = 0; r < 4; ++r) {
        const size_t row = m0 + wm * 64 + mt * 16 + quad * 4 + r;
#pragma unroll
        for (int nt = 0; nt < 4; ++nt) {
          const int cg = n0 + wn * 64 + nt * 16 + col;
          if (cg < nValid) outF[row * (size_t)nValid + cg] = acc[mt][nt][r];
        }
      }
  }
}

__global__ void f32_to_bf16(const float* __restrict__ in, unsigned short* __restrict__ out, int n4) {
  const int i = blockIdx.x * 256 + threadIdx.x;   // 4 elements per thread
  if (i >= n4) return;
  const float4 v = ((const float4*)in)[i];
  uint2 p;
  p.x = pk2(v.x, v.y);
  p.y = pk2(v.z, v.w);
  ((uint2*)out)[i] = p;
}

__global__ void bucket_fill(const int* __restrict__ rows, int nnz,
                            int* __restrict__ cnt, int* __restrict__ bucket) {
  const int e = blockIdx.x * 256 + threadIdx.x;
  if (e >= nnz) return;
  const int r = rows[e];
  if ((unsigned)r >= (unsigned)N1) return;
  const int pos = atomicAdd(&cnt[r], 1);
  if (pos < CAP) bucket[r * CAP + pos] = e;
}

// one block (256 thr) per graph row; thread t owns cols 4t..4t+3 (fp32 H0)
__global__ void build_graph(const int* __restrict__ cols,
                            const float* __restrict__ values,
                            const float* __restrict__ H0,
                            const float* __restrict__ gbias,
                            const int* __restrict__ cnt,
                            const int* __restrict__ bucket,
                            unsigned short* __restrict__ graph) {
  __shared__ int s_col[CAP];
  __shared__ float s_val[CAP];
  const int r = blockIdx.x;
  const int t = threadIdx.x;
  int n = (r < N1) ? cnt[r] : 0;
  if (n > CAP) n = CAP;
  if (t < n) {
    const int e = bucket[r * CAP + t];
    s_col[t] = cols[e];
    s_val[t] = values[e];
  }
  __syncthreads();
  float4 a = *(const float4*)(gbias + t * 4);
  for (int i = 0; i < n; ++i) {
    const int c = s_col[i];
    const float f = s_val[i];
    const float4 hv = *(const float4*)(H0 + (size_t)c * 1024 + t * 4);
    a.x += f * hv.x;
    a.y += f * hv.y;
    a.z += f * hv.z;
    a.w += f * hv.w;
  }
  uint2 p;
  p.x = pk2(a.x, a.y);
  p.y = pk2(a.z, a.w);
  *(uint2*)(graph + (size_t)r * 1024 + t * 4) = p;
}

__global__ void normalize_rows(const float* __restrict__ x, unsigned short* __restrict__ phrase) {
  const int b = blockIdx.x;
  const int t = threadIdx.x;
  const float4 v = *(const float4*)(x + (size_t)b * 1024 + t * 4);
  float ss = v.x * v.x + v.y * v.y + v.z * v.z + v.w * v.w;
#pragma unroll
  for (int o = 32; o > 0; o >>= 1) ss += __shfl_down(ss, o, 64);
  __shared__ float sred[4];
  if ((t & 63) == 0) sred[t >> 6] = ss;
  __syncthreads();
  const float tot = sred[0] + sred[1] + sred[2] + sred[3];
  const float inv = 1.0f / fmaxf(sqrtf(tot), 1e-12f);
  uint2 p;
  p.x = pk2(v.x * inv, v.y * inv);
  p.y = pk2(v.z * inv, v.w * inv);
  *(uint2*)(phrase + (size_t)b * 1024 + t * 4) = p;
}

extern "C" void kernel_launch(void* const* d_in, const int* in_sizes, int n_in,
                              void* d_out, int out_size, void* d_ws, size_t ws_size,
                              hipStream_t stream) {
  const float* data   = (const float*)d_in[0];   // (2048,32,1024) fp32
  // d_in[1] = seq_len: unused by the reference
  const float* conv_w = (const float*)d_in[2];   // (1024,1024) fp32
  const float* conv_b = (const float*)d_in[3];   // (1024,) fp32
  const float* lin_w  = (const float*)d_in[4];   // (1024,1024) fp32
  const float* lin_b  = (const float*)d_in[5];   // (1024,) fp32
  const float* gbias  = (const float*)d_in[6];   // (1024,) fp32
  const float* H0     = (const float*)d_in[7];   // (15001,1024) fp32
  const int* indices  = (const int*)d_in[8];     // (2, NNZ) int32
  const float* values = (const float*)d_in[9];   // (NNZ,) fp32
  float* out = (float*)d_out;                    // (2048,15001) fp32

  const int NNZ = in_sizes[9];

  char* ws = (char*)d_ws;
  char* ws0 = ws;
  unsigned short* conv_wb = (unsigned short*)ws; ws += (size_t)1024 * 1024 * 2;  // 2 MB
  unsigned short* lin_wb  = (unsigned short*)ws; ws += (size_t)1024 * 1024 * 2;  // 2 MB
  unsigned short* pooled  = (unsigned short*)ws; ws += (size_t)2048 * 1024 * 2;  // 4 MB
  float* xbuf             = (float*)ws;          ws += (size_t)2048 * 1024 * 4;  // 8 MB
  unsigned short* phrase  = (unsigned short*)ws; ws += (size_t)2048 * 1024 * 2;  // 4 MB
  unsigned short* graph   = (unsigned short*)ws; ws += (size_t)NPAD * 1024 * 2;  // ~31 MB
  int* cnt                = (int*)ws;            ws += (size_t)NPAD * 4;
  int* bucket             = (int*)ws;            ws += (size_t)NPAD * CAP * 4;   // ~5.8 MB

  // optional bf16 copy of data (134 MB) — only if workspace allows
  const size_t dataBfBytes = (size_t)2048 * 32 * 1024 * 2;
  unsigned short* data_bf = nullptr;
  if (ws_size >= (size_t)(ws - ws0) + dataBfBytes) {
    data_bf = (unsigned short*)ws;
    ws += dataBfBytes;
  }

  // --- weight conversion fp32 -> bf16 ---
  f32_to_bf16<<<1024, 256, 0, stream>>>(conv_w, conv_wb, 1024 * 1024 / 4);
  f32_to_bf16<<<1024, 256, 0, stream>>>(lin_w, lin_wb, 1024 * 1024 / 4);

  // --- sparse graph build ---
  hipMemsetAsync(cnt, 0, (size_t)NPAD * 4, stream);
  bucket_fill<<<(NNZ + 255) / 256, 256, 0, stream>>>(indices, NNZ, cnt, bucket);
  build_graph<<<NPAD, 256, 0, stream>>>(indices + NNZ, values, H0, gbias, cnt, bucket, graph);

  // --- CNN phrase encoder ---
  if (data_bf) {
    // pre-convert data to bf16 (one pass; GEMM A-reads then hit L2/L3)
    f32_to_bf16<<<(2048 * 32 * 1024 / 4 + 255) / 256, 256, 0, stream>>>(
        data, data_bf, 2048 * 32 * 1024 / 4);
    gemm_bt<3><<<dim3(8, 512), 256, 0, stream>>>(data_bf, conv_wb, conv_b, nullptr, pooled, 1024);
  } else {
    gemm_bt<0><<<dim3(8, 512), 256, 0, stream>>>(data, conv_wb, conv_b, nullptr, pooled, 1024);
  }
  gemm_bt<1><<<dim3(8, 16), 256, 0, stream>>>(pooled, lin_wb, lin_b, xbuf, nullptr, 1024);
  normalize_rows<<<2048, 256, 0, stream>>>(xbuf, phrase);

  // --- bilinear score ---
  gemm_bt<2><<<dim3(118, 16), 256, 0, stream>>>(phrase, graph, nullptr, out, nullptr, N1);
}

// Round 5
// 1003.484 us; speedup vs baseline: 1.0241x; 1.0241x over previous
//
#include <hip/hip_runtime.h>
#include <stdint.h>

typedef __attribute__((ext_vector_type(8))) __bf16 bf16x8;
typedef __attribute__((ext_vector_type(4))) float floatx4;

#define GLOBAL_AS __attribute__((address_space(1)))
#define LDS_AS __attribute__((address_space(3)))

#define CAP 96          // edge bucket capacity per row (Poisson lambda=16 -> overflow P ~1e-14)
#define N1 15001        // graph rows
#define NPAD 15104      // 118 * 128

__device__ __forceinline__ unsigned short f2bf(float x) {
  unsigned int u = __builtin_bit_cast(unsigned int, x);
  u += 0x7FFFu + ((u >> 16) & 1u);   // round-to-nearest-even
  return (unsigned short)(u >> 16);
}
__device__ __forceinline__ unsigned int pk2(float lo, float hi) {
  return (unsigned)f2bf(lo) | ((unsigned)f2bf(hi) << 16);
}

// Stage an NROWx32 bf16 tile (row-major, ld) into LDS chunks [kg][m], kg=k>>3,
// each chunk 16B (one row's 8 bf16 at k-octet kg). global_load_lds w=16:
// dst = wave-uniform base + lane*16. Issues NROW/128 vmem instrs per wave.
template <int NROW>
__device__ __forceinline__ void stage_tile(const unsigned short* g, int ld, int row0, int k0,
                                           bf16x8* lds, int tid) {
  const int lane = tid & 63;
  const int w = tid >> 6;
#pragma unroll
  for (int j = 0; j < NROW / 64; ++j) {
    const int c = j * 256 + w * 64;        // wave-uniform chunk base
    const int kg = c / NROW;
    const int mbase = c % NROW;
    const unsigned short* src = g + ((size_t)(row0 + mbase + lane) * ld + k0 + kg * 8);
    __builtin_amdgcn_global_load_lds((const GLOBAL_AS void*)src, (LDS_AS void*)(lds + c),
                                     16, 0, 0);
  }
}

// C = A(MxK) * B(NxK)^T, K=1024, 256x128 tile, 256 thr (4 waves), per-wave 128x64
// output (acc[8][4] of 16x16x32 MFMA). LDS-read:MFMA ratio 44 FLOP/B (vs 32 at
// 64x64/wave) -> MfmaUtil ceiling ~2x the old 128x128 tile.
// 2-buffer LDS, stage-ahead prefetch (issue t+1 before computing t).
// Bijective y-stripe XCD swizzle (needs gridDim.y % 8 == 0).
// MODE 0: A fp32 (convert-stage); epilogue bias+max-over-32rows+relu -> bf16 pooled
// MODE 1: A bf16; epilogue bias+relu -> fp32 outF (ld 1024)
// MODE 2: A bf16; plain fp32 store, ld nValid, col guard
// MODE 3: A bf16; epilogue bias+max-over-32rows+relu -> bf16 pooled
template <int MODE>
__launch_bounds__(256, 2)
__global__ void gemm_bt(const void* __restrict__ Aptr,
                        const unsigned short* __restrict__ Bm,
                        const float* __restrict__ bias,
                        float* __restrict__ outF,
                        unsigned short* __restrict__ outU,
                        int nValid) {
  __shared__ bf16x8 As[2][1024];   // [buf][kg(4)][m(256)] chunks, 32 KB
  __shared__ bf16x8 Bs[2][512];    // [buf][kg(4)][n(128)] chunks, 16 KB
  const int tid = threadIdx.x;
  const int lane = tid & 63;
  const int w = tid >> 6;
  const int wm = w >> 1, wn = w & 1;        // wave: rows wm*128..+127, cols wn*64..+63
  const int quad = lane >> 4, col = lane & 15;

  int bx = blockIdx.x, by = blockIdx.y;
  if ((gridDim.y & 7) == 0) {
    const unsigned L = (unsigned)by * gridDim.x + bx;   // original linear id
    const unsigned i = L >> 3, xk = L & 7;              // xcd = L % 8 (round-robin)
    bx = i % gridDim.x;
    by = (i / gridDim.x) * 8 + xk;                      // bijective: gy % 8 == 0
  }
  const int m0 = by * 256, n0 = bx * 128;
  const int K = 1024;

  floatx4 acc[8][4];
#pragma unroll
  for (int a = 0; a < 8; ++a)
#pragma unroll
    for (int b = 0; b < 4; ++b) acc[a][b] = 0;

  auto stage = [&](int buf, int k0) {
    if (MODE == 0) {
      // A fp32: thread owns one row, converts its 32 k-vals into 4 chunks
      const int row = tid;
      const float* src = (const float*)Aptr + (size_t)(m0 + row) * K + k0;
      float4 v[8];
#pragma unroll
      for (int j = 0; j < 8; ++j) v[j] = ((const float4*)src)[j];
      stage_tile<128>(Bm, K, n0, k0, Bs[buf], tid);   // overlap B DMA with A convert
#pragma unroll
      for (int kg = 0; kg < 4; ++kg) {
        uint4 cc;
        cc.x = pk2(v[2 * kg].x, v[2 * kg].y);
        cc.y = pk2(v[2 * kg].z, v[2 * kg].w);
        cc.z = pk2(v[2 * kg + 1].x, v[2 * kg + 1].y);
        cc.w = pk2(v[2 * kg + 1].z, v[2 * kg + 1].w);
        ((uint4*)As[buf])[kg * 256 + row] = cc;
      }
    } else {
      stage_tile<256>((const unsigned short*)Aptr, K, m0, k0, As[buf], tid);
      stage_tile<128>(Bm, K, n0, k0, Bs[buf], tid);
    }
  };

  stage(0, 0);                                // prologue: fill buf0
  int cur = 0;
  for (int k0 = 0; k0 < K; k0 += 32) {
    __syncthreads();                          // buf[cur] ready (drains vmcnt+lgkm)
    if (k0 + 32 < K) stage(cur ^ 1, k0 + 32); // issue next tile BEFORE computing
    bf16x8 af[8], bfr[4];
#pragma unroll
    for (int t = 0; t < 8; ++t) af[t] = As[cur][quad * 256 + wm * 128 + t * 16 + col];
#pragma unroll
    for (int t = 0; t < 4; ++t) bfr[t] = Bs[cur][quad * 128 + wn * 64 + t * 16 + col];
#pragma unroll
    for (int mt = 0; mt < 8; ++mt)
#pragma unroll
      for (int nt = 0; nt < 4; ++nt)
        acc[mt][nt] = __builtin_amdgcn_mfma_f32_16x16x32_bf16(af[mt], bfr[nt], acc[mt][nt], 0, 0, 0);
    cur ^= 1;
  }

  // D layout: row = quad*4 + reg, col = lane&15
  if (MODE == 0 || MODE == 3) {
    float bv[4];
#pragma unroll
    for (int nt = 0; nt < 4; ++nt) bv[nt] = bias[n0 + wn * 64 + nt * 16 + col];
#pragma unroll
    for (int g = 0; g < 4; ++g) {          // four 32-row (one-seq) groups per wave
#pragma unroll
      for (int nt = 0; nt < 4; ++nt) {
        float v = -3.4e38f;
#pragma unroll
        for (int mh = 0; mh < 2; ++mh) {
          const int mt = 2 * g + mh;
#pragma unroll
          for (int r = 0; r < 4; ++r) v = fmaxf(v, acc[mt][nt][r]);
        }
        v += bv[nt];                        // max(x)+b == max(x+b)
        v = fmaxf(v, __shfl_xor(v, 16, 64));
        v = fmaxf(v, __shfl_xor(v, 32, 64));
        v = fmaxf(v, 0.0f);                 // relu after max (monotone)
        if (quad == 0) {
          const int b = (m0 >> 5) + wm * 4 + g;
          outU[b * 1024 + n0 + wn * 64 + nt * 16 + col] = f2bf(v);
        }
      }
    }
  } else if (MODE == 1) {
    float bv[4];
#pragma unroll
    for (int nt = 0; nt < 4; ++nt) bv[nt] = bias[n0 + wn * 64 + nt * 16 + col];
#pragma unroll
    for (int mt = 0; mt < 8; ++mt)
#pragma unroll
      for (int r = 0; r < 4; ++r) {
        const int row = m0 + wm * 128 + mt * 16 + quad * 4 + r;
#pragma unroll
        for (int nt = 0; nt < 4; ++nt)
          outF[(size_t)row * 1024 + n0 + wn * 64 + nt * 16 + col] =
              fmaxf(acc[mt][nt][r] + bv[nt], 0.0f);
      }
  } else {
#pragma unroll
    for (int mt = 0; mt < 8; ++mt)
#pragma unroll
      for (int r = 0; r < 4; ++r) {
        const size_t row = m0 + wm * 128 + mt * 16 + quad * 4 + r;
#pragma unroll
        for (int nt = 0; nt < 4; ++nt) {
          const int cg = n0 + wn * 64 + nt * 16 + col;
          if (cg < nValid) outF[row * (size_t)nValid + cg] = acc[mt][nt][r];
        }
      }
  }
}

__global__ void f32_to_bf16(const float* __restrict__ in, unsigned short* __restrict__ out, int n4) {
  const int i = blockIdx.x * 256 + threadIdx.x;   // 4 elements per thread
  if (i >= n4) return;
  const float4 v = ((const float4*)in)[i];
  uint2 p;
  p.x = pk2(v.x, v.y);
  p.y = pk2(v.z, v.w);
  ((uint2*)out)[i] = p;
}

__global__ void bucket_fill(const int* __restrict__ rows, int nnz,
                            int* __restrict__ cnt, int* __restrict__ bucket) {
  const int e = blockIdx.x * 256 + threadIdx.x;
  if (e >= nnz) return;
  const int r = rows[e];
  if ((unsigned)r >= (unsigned)N1) return;
  const int pos = atomicAdd(&cnt[r], 1);
  if (pos < CAP) bucket[r * CAP + pos] = e;
}

// one block (256 thr) per graph row; thread t owns cols 4t..4t+3 (fp32 H0)
__global__ void build_graph(const int* __restrict__ cols,
                            const float* __restrict__ values,
                            const float* __restrict__ H0,
                            const float* __restrict__ gbias,
                            const int* __restrict__ cnt,
                            const int* __restrict__ bucket,
                            unsigned short* __restrict__ graph) {
  __shared__ int s_col[CAP];
  __shared__ float s_val[CAP];
  const int r = blockIdx.x;
  const int t = threadIdx.x;
  int n = (r < N1) ? cnt[r] : 0;
  if (n > CAP) n = CAP;
  if (t < n) {
    const int e = bucket[r * CAP + t];
    s_col[t] = cols[e];
    s_val[t] = values[e];
  }
  __syncthreads();
  float4 a = *(const float4*)(gbias + t * 4);
  for (int i = 0; i < n; ++i) {
    const int c = s_col[i];
    const float f = s_val[i];
    const float4 hv = *(const float4*)(H0 + (size_t)c * 1024 + t * 4);
    a.x += f * hv.x;
    a.y += f * hv.y;
    a.z += f * hv.z;
    a.w += f * hv.w;
  }
  uint2 p;
  p.x = pk2(a.x, a.y);
  p.y = pk2(a.z, a.w);
  *(uint2*)(graph + (size_t)r * 1024 + t * 4) = p;
}

__global__ void normalize_rows(const float* __restrict__ x, unsigned short* __restrict__ phrase) {
  const int b = blockIdx.x;
  const int t = threadIdx.x;
  const float4 v = *(const float4*)(x + (size_t)b * 1024 + t * 4);
  float ss = v.x * v.x + v.y * v.y + v.z * v.z + v.w * v.w;
#pragma unroll
  for (int o = 32; o > 0; o >>= 1) ss += __shfl_down(ss, o, 64);
  __shared__ float sred[4];
  if ((t & 63) == 0) sred[t >> 6] = ss;
  __syncthreads();
  const float tot = sred[0] + sred[1] + sred[2] + sred[3];
  const float inv = 1.0f / fmaxf(sqrtf(tot), 1e-12f);
  uint2 p;
  p.x = pk2(v.x * inv, v.y * inv);
  p.y = pk2(v.z * inv, v.w * inv);
  *(uint2*)(phrase + (size_t)b * 1024 + t * 4) = p;
}

extern "C" void kernel_launch(void* const* d_in, const int* in_sizes, int n_in,
                              void* d_out, int out_size, void* d_ws, size_t ws_size,
                              hipStream_t stream) {
  const float* data   = (const float*)d_in[0];   // (2048,32,1024) fp32
  // d_in[1] = seq_len: unused by the reference
  const float* conv_w = (const float*)d_in[2];   // (1024,1024) fp32
  const float* conv_b = (const float*)d_in[3];   // (1024,) fp32
  const float* lin_w  = (const float*)d_in[4];   // (1024,1024) fp32
  const float* lin_b  = (const float*)d_in[5];   // (1024,) fp32
  const float* gbias  = (const float*)d_in[6];   // (1024,) fp32
  const float* H0     = (const float*)d_in[7];   // (15001,1024) fp32
  const int* indices  = (const int*)d_in[8];     // (2, NNZ) int32
  const float* values = (const float*)d_in[9];   // (NNZ,) fp32
  float* out = (float*)d_out;                    // (2048,15001) fp32

  const int NNZ = in_sizes[9];

  char* ws = (char*)d_ws;
  char* ws0 = ws;
  unsigned short* conv_wb = (unsigned short*)ws; ws += (size_t)1024 * 1024 * 2;  // 2 MB
  unsigned short* lin_wb  = (unsigned short*)ws; ws += (size_t)1024 * 1024 * 2;  // 2 MB
  unsigned short* pooled  = (unsigned short*)ws; ws += (size_t)2048 * 1024 * 2;  // 4 MB
  float* xbuf             = (float*)ws;          ws += (size_t)2048 * 1024 * 4;  // 8 MB
  unsigned short* phrase  = (unsigned short*)ws; ws += (size_t)2048 * 1024 * 2;  // 4 MB
  unsigned short* graph   = (unsigned short*)ws; ws += (size_t)NPAD * 1024 * 2;  // ~31 MB
  int* cnt                = (int*)ws;            ws += (size_t)NPAD * 4;
  int* bucket             = (int*)ws;            ws += (size_t)NPAD * CAP * 4;   // ~5.8 MB

  // optional bf16 copy of data (134 MB) — only if workspace allows
  const size_t dataBfBytes = (size_t)2048 * 32 * 1024 * 2;
  unsigned short* data_bf = nullptr;
  if (ws_size >= (size_t)(ws - ws0) + dataBfBytes) {
    data_bf = (unsigned short*)ws;
    ws += dataBfBytes;
  }

  // --- weight conversion fp32 -> bf16 ---
  f32_to_bf16<<<1024, 256, 0, stream>>>(conv_w, conv_wb, 1024 * 1024 / 4);
  f32_to_bf16<<<1024, 256, 0, stream>>>(lin_w, lin_wb, 1024 * 1024 / 4);

  // --- sparse graph build ---
  hipMemsetAsync(cnt, 0, (size_t)NPAD * 4, stream);
  bucket_fill<<<(NNZ + 255) / 256, 256, 0, stream>>>(indices, NNZ, cnt, bucket);
  build_graph<<<NPAD, 256, 0, stream>>>(indices + NNZ, values, H0, gbias, cnt, bucket, graph);

  // --- CNN phrase encoder ---
  if (data_bf) {
    // pre-convert data to bf16 (one pass; GEMM A-reads then hit L2/L3)
    f32_to_bf16<<<(2048 * 32 * 1024 / 4 + 255) / 256, 256, 0, stream>>>(
        data, data_bf, 2048 * 32 * 1024 / 4);
    gemm_bt<3><<<dim3(8, 256), 256, 0, stream>>>(data_bf, conv_wb, conv_b, nullptr, pooled, 1024);
  } else {
    gemm_bt<0><<<dim3(8, 256), 256, 0, stream>>>(data, conv_wb, conv_b, nullptr, pooled, 1024);
  }
  gemm_bt<1><<<dim3(8, 8), 256, 0, stream>>>(pooled, lin_wb, lin_b, xbuf, nullptr, 1024);
  normalize_rows<<<2048, 256, 0, stream>>>(xbuf, phrase);

  // --- bilinear score ---
  gemm_bt<2><<<dim3(118, 8), 256, 0, stream>>>(phrase, graph, nullptr, out, nullptr, N1);
}